// Round 6
// baseline (214.264 us; speedup 1.0000x reference)
//
#include <hip/hip_runtime.h>

#define T_LEN 2048
#define NCHUNK 16
#define CH_S 128      // stored steps per chunk
#define WARM 64       // warm-up steps (10.7*mu)
#define RK 16         // renorm every 16 steps (scale cancels in LLR)

// Butterfly sum across all 64 lanes; every lane gets the total. (ds_swizzle pipe)
__device__ __forceinline__ float wave_sum64(float v) {
    #pragma unroll
    for (int d = 1; d < 64; d <<= 1) v += __shfl_xor(v, d, 64);
    return v;
}

// v + v[lane^1] via DPP quad_perm [1,0,3,2] — VALU pipe, no DS op.
__device__ __forceinline__ float pair_sum_xor1(float v) {
    int r = __builtin_amdgcn_update_dpp(0, __float_as_int(v), 0xB1, 0xF, 0xF, true);
    return v + __int_as_float(r);
}

// cheap fp32 -> bf16 (round-half-up): 2 VALU ops
__device__ __forceinline__ unsigned short bf16_of(float f) {
    return (unsigned short)((__float_as_uint(f) + 0x8000u) >> 16);
}

// GEN_POLY = ('1111001','1011011'), mu=6, NS=64. State s: shift reg, newest bit = MSB.
// o0 parity mask 57, o1 mask 27. Branch metric (log2 domain):
// x_s = kE*la + (kE*c0)*l0 + (kE*c1)*l1 ; gamma(s,0)=2^x_s, gamma(s,1)=2^-x_s.
//
// One block per (b, chunk): wave0 = alpha (warm + 128 stored steps -> LDS tile),
// wave1 = beta (warm; then fused backward steps emitting LLRs from LDS alpha).
// llr_t = log(sum_s a_t[s] g0[s] B[s>>1]) - log(sum_s a_t[s] g1[s] B[32|(s>>1)]);
// all normalization scales cancel in the ratio.
__global__ __launch_bounds__(128, 4)
void bcjr_fused(const float* __restrict__ llr_ch,   // [B][2*T]
                const float* __restrict__ llr_a,    // [B][T]
                float* __restrict__ out)            // [B][T]
{
    __shared__ unsigned short lds_a[CH_S * 64];     // bf16 alpha tile (16 KiB)

    const int blk   = blockIdx.x;
    const int b     = blk >> 4;                     // NCHUNK = 16
    const int chunk = blk & (NCHUNK - 1);
    const int wave  = threadIdx.x >> 6;
    const int lane  = threadIdx.x & 63;

    const float c0 = 1.0f - 2.0f * (float)(__popc(lane & 57) & 1);
    const float c1 = 1.0f - 2.0f * (float)(__popc(lane & 27) & 1);
    const float kE = 0.5f * 1.442695040888963f;
    const float k0 = kE * c0, k1 = kE * c1;

    const float* chp = llr_ch + (size_t)b * (2 * T_LEN);
    const float* lap = llr_a  + (size_t)b * T_LEN;
    const int t0 = chunk * CH_S;

    const int bs0 = lane >> 1;          // beta gather sources
    const int bs1 = 32 + (lane >> 1);

    float state;

    if (wave == 0) {
        // ---------- alpha: warm-up + stored tile -> LDS ----------
        const int  fs0 = 2 * (lane & 31);
        const bool fhi = (lane >= 32);
        const int ts = (chunk == 0) ? t0 : t0 - WARM;
        state = (chunk == 0) ? ((lane == 0) ? 1.0f : 0.0f) : (1.0f / 64.0f);

        for (int g = ts; g < t0 + CH_S; g += RK) {
            const bool store = (g >= t0);
            #pragma unroll
            for (int h = 0; h < 2; ++h) {
                const int gb = g + 8 * h;
                const float4* c4 = (const float4*)(chp + 2 * gb);
                const float4* a4 = (const float4*)(lap + gb);
                float4 cc[4]; float4 aa[2];
                #pragma unroll
                for (int i = 0; i < 4; ++i) cc[i] = c4[i];
                #pragma unroll
                for (int i = 0; i < 2; ++i) aa[i] = a4[i];
                #pragma unroll
                for (int i = 0; i < 8; ++i) {
                    float l0 = (i & 1) ? cc[i >> 1].z : cc[i >> 1].x;
                    float l1 = (i & 1) ? cc[i >> 1].w : cc[i >> 1].y;
                    float la = ((const float*)aa)[i];
                    if (store) lds_a[(gb - t0 + i) * 64 + lane] = bf16_of(state);
                    float x   = fmaf(la, kE, fmaf(l0, k0, l1 * k1));
                    float g0v = exp2f(x);
                    float g1v = __builtin_amdgcn_rcpf(g0v);
                    float s0  = pair_sum_xor1(state * g0v);
                    float s1  = pair_sum_xor1(state * g1v);
                    float a0  = __shfl(s0, fs0, 64);
                    float a1  = __shfl(s1, fs0, 64);
                    state = fhi ? a1 : a0;
                }
            }
            float s = wave_sum64(state);
            state = state * __builtin_amdgcn_rcpf(s);
        }
    } else {
        // ---------- beta: warm-up only (before barrier) ----------
        state = 1.0f / 64.0f;           // exact beta_T for last chunk
        if (chunk != NCHUNK - 1) {
            for (int g = t0 + CH_S + WARM - RK; g >= t0 + CH_S; g -= RK) {
                #pragma unroll
                for (int h = 1; h >= 0; --h) {
                    const int gb = g + 8 * h;
                    const float4* c4 = (const float4*)(chp + 2 * gb);
                    const float4* a4 = (const float4*)(lap + gb);
                    float4 cc[4]; float4 aa[2];
                    #pragma unroll
                    for (int i = 0; i < 4; ++i) cc[i] = c4[i];
                    #pragma unroll
                    for (int i = 0; i < 2; ++i) aa[i] = a4[i];
                    #pragma unroll
                    for (int i = 7; i >= 0; --i) {
                        float l0 = (i & 1) ? cc[i >> 1].z : cc[i >> 1].x;
                        float l1 = (i & 1) ? cc[i >> 1].w : cc[i >> 1].y;
                        float la = ((const float*)aa)[i];
                        float x   = fmaf(la, kE, fmaf(l0, k0, l1 * k1));
                        float g0v = exp2f(x);
                        float g1v = __builtin_amdgcn_rcpf(g0v);
                        float t0v = __shfl(state, bs0, 64);
                        float t1v = __shfl(state, bs1, 64);
                        state = fmaf(g0v, t0v, g1v * t1v);
                    }
                }
                float s = wave_sum64(state);
                state = state * __builtin_amdgcn_rcpf(s);
            }
        }
    }

    __syncthreads();   // alpha tile visible to beta wave

    if (wave == 1) {
        // ---------- beta fused: state update + LLR emission ----------
        float* outp = out + (size_t)b * T_LEN;
        float keep = 0.0f;
        for (int g = t0 + CH_S - RK; g >= t0; g -= RK) {
            #pragma unroll
            for (int h = 1; h >= 0; --h) {
                const int gb = g + 8 * h;
                const float4* c4 = (const float4*)(chp + 2 * gb);
                const float4* a4 = (const float4*)(lap + gb);
                float4 cc[4]; float4 aa[2];
                #pragma unroll
                for (int i = 0; i < 4; ++i) cc[i] = c4[i];
                #pragma unroll
                for (int i = 0; i < 2; ++i) aa[i] = a4[i];
                #pragma unroll
                for (int i = 7; i >= 0; --i) {
                    const int t = gb + i;
                    float l0 = (i & 1) ? cc[i >> 1].z : cc[i >> 1].x;
                    float l1 = (i & 1) ? cc[i >> 1].w : cc[i >> 1].y;
                    float la = ((const float*)aa)[i];
                    float x   = fmaf(la, kE, fmaf(l0, k0, l1 * k1));
                    float g0v = exp2f(x);
                    float g1v = __builtin_amdgcn_rcpf(g0v);
                    float t0v = __shfl(state, bs0, 64);
                    float t1v = __shfl(state, bs1, 64);
                    float bg0 = g0v * t0v;
                    float bg1 = g1v * t1v;
                    float ar = __uint_as_float(((unsigned)lds_a[(t - t0) * 64 + lane]) << 16);
                    float n0 = wave_sum64(ar * bg0);
                    float n1 = wave_sum64(ar * bg1);
                    float llr = __logf(n0) - __logf(n1);
                    keep = (lane == (t & 63)) ? llr : keep;     // capture for coalesced store
                    state = bg0 + bg1;
                }
            }
            if ((g & 63) == 0) outp[g + lane] = keep;           // 64 llrs per store
            float s = wave_sum64(state);
            state = state * __builtin_amdgcn_rcpf(s);
        }
    }
}

extern "C" void kernel_launch(void* const* d_in, const int* in_sizes, int n_in,
                              void* d_out, int out_size, void* d_ws, size_t ws_size,
                              hipStream_t stream) {
    const float* llr_ch = (const float*)d_in[0];
    const float* llr_a  = (const float*)d_in[1];
    float* out = (float*)d_out;

    int B = in_sizes[0] / (2 * T_LEN);   // 256
    hipLaunchKernelGGL(bcjr_fused, dim3(B * NCHUNK), dim3(128), 0, stream,
                       llr_ch, llr_a, out);
}

// Round 7
// 131.600 us; speedup vs baseline: 1.6281x; 1.6281x over previous
//
#include <hip/hip_runtime.h>
#include <hip/hip_bf16.h>

#define T_LEN 2048
#define NSTATE 64
#define NCHUNK 16
#define CH_S 128      // stored steps per chunk
#define WARM 64       // warm-up steps (10.7*mu) before the stored region
#define RK 16         // renorm every 16 steps (scale cancels in LLR)

// Butterfly sum across all 64 lanes; every lane gets the total.
__device__ __forceinline__ float wave_sum64(float v) {
    #pragma unroll
    for (int d = 1; d < 64; d <<= 1) v += __shfl_xor(v, d, 64);
    return v;
}

// v + v[lane^1] via DPP quad_perm [1,0,3,2] — VALU pipe, no DS op.
__device__ __forceinline__ float pair_sum_xor1(float v) {
    int r = __builtin_amdgcn_update_dpp(0, __float_as_int(v), 0xB1, 0xF, 0xF, true);
    return v + __int_as_float(r);
}

// cheap fp32 -> bf16 (round-half-up): 2 VALU ops
__device__ __forceinline__ unsigned short bf16_of(float f) {
    return (unsigned short)((__float_as_uint(f) + 0x8000u) >> 16);
}
__device__ __forceinline__ float bf16_lo(unsigned u) { return __uint_as_float(u << 16); }
__device__ __forceinline__ float bf16_hi(unsigned u) { return __uint_as_float(u & 0xffff0000u); }

// GEN_POLY = ('1111001','1011011'), mu=6, NS=64.
// State s: shift register, most-recent bit = MSB (bit 5).
// o0 parity mask of s: 57 ; o1 mask: 27.
// log2-domain branch metric: x_s = kE*la + (kE*c0)*l0 + (kE*c1)*l1, kE = 0.5*log2(e)
// gamma(s,0) = 2^x_s ; gamma(s,1) = 2^-x_s.

// ---------------- Kernel A: chunked sweeps, branchless 16-step groups ----------------
// (identical to round-5 version: 67.5 us measured, VALU-issue-bound)
__global__ __launch_bounds__(256, 8)
void bcjr_sweep_kernel(const float* __restrict__ llr_ch,   // [B][2*T]
                       const float* __restrict__ llr_a,    // [B][T]
                       unsigned short* __restrict__ wsA,   // [B][T][64] bf16 alpha_t
                       unsigned short* __restrict__ wsB)   // [B][T][64] bf16 beta_{t+1}
{
    const int wave  = blockIdx.x * 4 + (threadIdx.x >> 6);
    const int lane  = threadIdx.x & 63;
    const int dir   = wave & 1;
    const int chunk = (wave >> 1) & (NCHUNK - 1);
    const int b     = wave >> 5;

    const float c0 = 1.0f - 2.0f * (float)(__popc(lane & 57) & 1);
    const float c1 = 1.0f - 2.0f * (float)(__popc(lane & 27) & 1);
    const float kE = 0.5f * 1.442695040888963f;
    const float k0 = kE * c0, k1 = kE * c1;

    const float* chp = llr_ch + (size_t)b * (2 * T_LEN);
    const float* lap = llr_a  + (size_t)b * T_LEN;

    if (dir == 0) {
        unsigned short* w = wsA + (size_t)b * T_LEN * NSTATE;
        const int  fs0 = 2 * (lane & 31);
        const bool fhi = (lane >= 32);
        const int t0 = chunk * CH_S;
        const int ts = (chunk == 0) ? t0 : t0 - WARM;
        float state = (chunk == 0) ? ((lane == 0) ? 1.0f : 0.0f) : (1.0f / 64.0f);

        for (int g = ts; g < t0 + CH_S; g += RK) {
            const bool store = (g >= t0);
            #pragma unroll
            for (int h = 0; h < 2; ++h) {
                const int gb = g + 8 * h;
                const float4* c4 = (const float4*)(chp + 2 * gb);
                const float4* a4 = (const float4*)(lap + gb);
                float4 cc[4], aa[2];
                #pragma unroll
                for (int i = 0; i < 4; ++i) cc[i] = c4[i];
                #pragma unroll
                for (int i = 0; i < 2; ++i) aa[i] = a4[i];
                unsigned short* wb = w + (size_t)gb * NSTATE + lane;
                #pragma unroll
                for (int i = 0; i < 8; ++i) {
                    float l0 = (i & 1) ? cc[i >> 1].z : cc[i >> 1].x;
                    float l1 = (i & 1) ? cc[i >> 1].w : cc[i >> 1].y;
                    float la = ((const float*)aa)[i];
                    if (store) wb[i * NSTATE] = bf16_of(state);   // alpha_t
                    float x   = fmaf(la, kE, fmaf(l0, k0, l1 * k1));
                    float g0v = exp2f(x);
                    float g1v = __builtin_amdgcn_rcpf(g0v);
                    float s0  = pair_sum_xor1(state * g0v);
                    float s1  = pair_sum_xor1(state * g1v);
                    float a0  = __shfl(s0, fs0, 64);
                    float a1  = __shfl(s1, fs0, 64);
                    state = fhi ? a1 : a0;
                }
            }
            float s = wave_sum64(state);
            state = state * __builtin_amdgcn_rcpf(s);
        }
    } else {
        unsigned short* w = wsB + (size_t)b * T_LEN * NSTATE;
        const int bs0 = lane >> 1;
        const int bs1 = 32 + (lane >> 1);
        const int t0 = chunk * CH_S;
        const int te = (chunk == NCHUNK - 1) ? (t0 + CH_S) : (t0 + CH_S + WARM);
        float state = 1.0f / 64.0f;

        for (int g = te - RK; g >= t0; g -= RK) {
            const bool store = (g < t0 + CH_S);
            #pragma unroll
            for (int h = 1; h >= 0; --h) {
                const int gb = g + 8 * h;
                const float4* c4 = (const float4*)(chp + 2 * gb);
                const float4* a4 = (const float4*)(lap + gb);
                float4 cc[4], aa[2];
                #pragma unroll
                for (int i = 0; i < 4; ++i) cc[i] = c4[i];
                #pragma unroll
                for (int i = 0; i < 2; ++i) aa[i] = a4[i];
                unsigned short* wb = w + (size_t)gb * NSTATE + lane;
                #pragma unroll
                for (int i = 7; i >= 0; --i) {
                    float l0 = (i & 1) ? cc[i >> 1].z : cc[i >> 1].x;
                    float l1 = (i & 1) ? cc[i >> 1].w : cc[i >> 1].y;
                    float la = ((const float*)aa)[i];
                    if (store) wb[i * NSTATE] = bf16_of(state);   // beta_{t+1}
                    float x   = fmaf(la, kE, fmaf(l0, k0, l1 * k1));
                    float g0v = exp2f(x);
                    float g1v = __builtin_amdgcn_rcpf(g0v);
                    float t0v = __shfl(state, bs0, 64);
                    float t1v = __shfl(state, bs1, 64);
                    state = fmaf(g0v, t0v, g1v * t1v);
                }
            }
            float s = wave_sum64(state);
            state = state * __builtin_amdgcn_rcpf(s);
        }
    }
}

// ---------------- Kernel B: 8 threads per (b,t), coalesced loads ----------------
// Thread q of 8 owns states j=4q..4q+3 (A-dwords) and the matching beta dwords.
// Parity structure: for j=4q+m, p0 = parity(q) (m-independent), p1 = (m&1)^parity(q&3)
// -> per-thread gamma table = 2 exp2 + cheap muls, all per-m picks compile-time.
__global__ __launch_bounds__(256, 8)
void bcjr_llr_kernel(const float* __restrict__ llr_ch,
                     const float* __restrict__ llr_a,
                     const unsigned short* __restrict__ wsA,
                     const unsigned short* __restrict__ wsB,
                     float* __restrict__ out)
{
    const int gid = blockIdx.x * 256 + threadIdx.x;
    const int rt  = gid >> 3;          // = b*T + t
    const int q   = gid & 7;

    // coalesced loads: A 1 KiB contiguous per wave; B two dwordx2 streams
    const uint4 av = ((const uint4*)(wsA + (size_t)rt * NSTATE))[q];        // A dwords 4q..4q+3
    const uint2 b0 = ((const uint2*)(wsB + (size_t)rt * NSTATE))[q];        // B dwords 2q,2q+1
    const uint2 b1 = ((const uint2*)(wsB + (size_t)rt * NSTATE + 32))[q];   // B dwords 16+2q,17+2q

    float2 c2 = ((const float2*)llr_ch)[rt];
    float  la = llr_a[rt];
    const float kE = 0.5f * 1.442695040888963f;
    float E = la * kE, X0 = c2.x * kE, X1 = c2.y * kE;

    // signed X0/X1 for this thread's parity class
    const unsigned p0 = (unsigned)(__popc(q) & 1) << 31;
    const unsigned p1 = (unsigned)(__popc(q & 3) & 1) << 31;
    float sX0 = __uint_as_float(__float_as_uint(X0) ^ p0);   // (1-2*parity(q))   * X0
    float sX1 = __uint_as_float(__float_as_uint(X1) ^ p1);   // (1-2*parity(q&3)) * X1

    float Ge = exp2f(E + sX0 + sX1);            // gamma0 for m even
    float Go = exp2f(E + sX0 - sX1);            // gamma0 for m odd
    float Re = __builtin_amdgcn_rcpf(Ge);       // gamma1 for m even
    float Ro = __builtin_amdgcn_rcpf(Go);
    float e2E = exp2f(E + E);
    float r2E = __builtin_amdgcn_rcpf(e2E);
    // G[k0]=Gx, G[k0^3]=e2E*Rx, R[k0]=Rx, R[k0^3]=r2E*Gx  (x = e/o by m&1)
    float GBe = e2E * Re, GBo = e2E * Ro;
    float RBe = r2E * Ge, RBo = r2E * Go;

    const unsigned aw[4]  = { av.x, av.y, av.z, av.w };
    const unsigned bw0[2] = { b0.x, b0.y };
    const unsigned bw1[2] = { b1.x, b1.y };

    float n0 = 0.0f, n1 = 0.0f;
    #pragma unroll
    for (int m = 0; m < 4; ++m) {
        float GA = (m & 1) ? Go  : Ge;
        float GB = (m & 1) ? GBo : GBe;
        float RA = (m & 1) ? Ro  : Re;
        float RB = (m & 1) ? RBo : RBe;
        float a0 = bf16_lo(aw[m]);                 // alpha[2j],  j=4q+m
        float a1 = bf16_hi(aw[m]);                 // alpha[2j+1]
        unsigned bd0 = bw0[m >> 1];                // beta[j]
        unsigned bd1 = bw1[m >> 1];                // beta[32+j]
        float b0v = (m & 1) ? bf16_hi(bd0) : bf16_lo(bd0);
        float b1v = (m & 1) ? bf16_hi(bd1) : bf16_lo(bd1);
        n0 = fmaf(b0v, fmaf(a0, GA, a1 * GB), n0);
        n1 = fmaf(b1v, fmaf(a0, RA, a1 * RB), n1);
    }

    // reduce across the 8-lane group (widths 1,2,4 -> DPP-cheap)
    #pragma unroll
    for (int d = 1; d < 8; d <<= 1) {
        n0 += __shfl_xor(n0, d, 64);
        n1 += __shfl_xor(n1, d, 64);
    }
    if (q == 0) out[rt] = __logf(n0) - __logf(n1);
}

extern "C" void kernel_launch(void* const* d_in, const int* in_sizes, int n_in,
                              void* d_out, int out_size, void* d_ws, size_t ws_size,
                              hipStream_t stream) {
    const float* llr_ch = (const float*)d_in[0];
    const float* llr_a  = (const float*)d_in[1];
    float* out = (float*)d_out;

    int B = in_sizes[0] / (2 * T_LEN);   // 256
    const size_t traj_bytes = (size_t)B * T_LEN * NSTATE * sizeof(unsigned short); // 64 MiB

    unsigned short* wsA = (unsigned short*)d_ws;
    unsigned short* wsB = (unsigned short*)((char*)d_ws + traj_bytes);

    int n_waves = B * NCHUNK * 2;        // 8192 sweep waves
    hipLaunchKernelGGL(bcjr_sweep_kernel, dim3(n_waves / 4), dim3(256), 0, stream,
                       llr_ch, llr_a, wsA, wsB);

    int n_thr = B * T_LEN * 8;           // 8 threads per (b,t)
    hipLaunchKernelGGL(bcjr_llr_kernel, dim3(n_thr / 256), dim3(256), 0, stream,
                       llr_ch, llr_a, wsA, wsB, out);
}